// Round 9
// baseline (420.404 us; speedup 1.0000x reference)
//
#include <hip/hip_runtime.h>
#include <hip/hip_bf16.h>
#include <hip/hip_fp16.h>
#include <hip/hip_cooperative_groups.h>

namespace cg = cooperative_groups;

// ResidualGNN: 2x GCNConv(128->128, relu) + FC(128->3, tanh), N=100000, E=1.6M, fp32.
// R8: cooperative front-end kernel fusing [deg_rank || gemm1] / scan / [finish || fill]
//     with grid syncs; gather1 consumes unscaled H with per-edge dinv (drops the
//     H-rescale pass); rank stored as ushort; GEMM1 tiles claimed via atomic counter.

#define NODE_F 128

typedef __attribute__((ext_vector_type(8))) short bf16x8;
typedef __attribute__((ext_vector_type(8))) unsigned short u16x8;
typedef __attribute__((ext_vector_type(4))) float f32x4;

__device__ inline unsigned short bf16_rn(float x) {
    unsigned u = __builtin_bit_cast(unsigned, x);
    unsigned r = (u + 0x7fffu + ((u >> 16) & 1u)) >> 16;
    return (unsigned short)r;
}
__device__ inline float bf16_to_f(unsigned short h) {
    unsigned u = (unsigned)h << 16;
    return __builtin_bit_cast(float, u);
}
__device__ inline void acc8_h(float a[8], uint4 v, float s) {
    unsigned vv[4] = {v.x, v.y, v.z, v.w};
    #pragma unroll
    for (int j = 0; j < 4; ++j) {
        float2 f = __half22float2(__builtin_bit_cast(__half2, vv[j]));
        a[2 * j]     += f.x * s;
        a[2 * j + 1] += f.y * s;
    }
}

// ---- W -> bf16 hi/lo transposed; also zero the gemm work counter --------

__global__ __launch_bounds__(256) void wconv_kernel(const float* __restrict__ W1,
                                                    const float* __restrict__ W2,
                                                    unsigned short* __restrict__ WhiT,
                                                    unsigned short* __restrict__ WloT,
                                                    int* __restrict__ counter)
{
    if (blockIdx.x == 0 && threadIdx.x == 0) *counter = 0;
    const float* W = blockIdx.x ? W2 : W1;
    unsigned short* hiT = WhiT + blockIdx.x * 128 * 128;
    unsigned short* loT = WloT + blockIdx.x * 128 * 128;
    int tid = threadIdx.x;
    for (int i = tid; i < 128 * 128; i += 256) {
        int k = i >> 7, n = i & 127;
        float x = W[i];
        unsigned short hi = bf16_rn(x);
        float lo = x - bf16_to_f(hi);
        hiT[n * 128 + k] = hi;
        loT[n * 128 + k] = bf16_rn(lo);
    }
}

// ---- GEMM body (64 rows x 128 cols per tile, 4 waves) -------------------

template<bool SPLIT_IN, bool SCALE_OUT>
__device__ __forceinline__ void gemm_body(
    const float* __restrict__ Xf,
    const unsigned short* __restrict__ Xhi_g, const unsigned short* __restrict__ Xlo_g,
    const unsigned short* __restrict__ WhiT, const unsigned short* __restrict__ WloT,
    const float* __restrict__ dinv,
    __half* __restrict__ Hout, int N, int bid,
    unsigned short* xhi, unsigned short* xlo)
{
    const int tid  = threadIdx.x;
    const int lane = tid & 63;
    const int w    = tid >> 6;
    const int rbase = bid * 64;

    bf16x8 bhi[2][4], blo[2][4];
    {
        int n0   = w * 32 + (lane & 15);
        int koct = (lane >> 4) * 8;
        #pragma unroll
        for (int nt = 0; nt < 2; ++nt) {
            #pragma unroll
            for (int kk = 0; kk < 4; ++kk) {
                size_t o = (size_t)(n0 + nt * 16) * 128 + kk * 32 + koct;
                bhi[nt][kk] = *reinterpret_cast<const bf16x8*>(WhiT + o);
                blo[nt][kk] = *reinterpret_cast<const bf16x8*>(WloT + o);
            }
        }
    }

    if (!SPLIT_IN) {
        #pragma unroll
        for (int it = 0; it < 8; ++it) {
            int f   = it * 256 + tid;
            int row = f >> 5;
            int k4  = f & 31;
            float4 v = make_float4(0.f, 0.f, 0.f, 0.f);
            if (rbase + row < N)
                v = *reinterpret_cast<const float4*>(Xf + (size_t)(rbase + row) * NODE_F + k4 * 4);
            float xs[4] = {v.x, v.y, v.z, v.w};
            ushort4 h4, l4;
            unsigned short* hp = &h4.x;
            unsigned short* lp = &l4.x;
            #pragma unroll
            for (int j = 0; j < 4; ++j) {
                unsigned short hi = bf16_rn(xs[j]);
                hp[j] = hi;
                lp[j] = bf16_rn(xs[j] - bf16_to_f(hi));
            }
            int byte = row * 256 + ((k4 * 8) ^ ((row & 7) << 4));
            *reinterpret_cast<ushort4*>(reinterpret_cast<char*>(xhi) + byte) = h4;
            *reinterpret_cast<ushort4*>(reinterpret_cast<char*>(xlo) + byte) = l4;
        }
    } else {
        #pragma unroll
        for (int it = 0; it < 4; ++it) {
            int idx = it * 256 + tid;
            int row = idx >> 4;
            int k8  = idx & 15;
            u16x8 h = {0, 0, 0, 0, 0, 0, 0, 0};
            u16x8 l = {0, 0, 0, 0, 0, 0, 0, 0};
            if (rbase + row < N) {
                size_t g = (size_t)(rbase + row) * NODE_F + k8 * 8;
                h = *reinterpret_cast<const u16x8*>(Xhi_g + g);
                l = *reinterpret_cast<const u16x8*>(Xlo_g + g);
            }
            int byte = row * 256 + ((k8 * 16) ^ ((row & 7) << 4));
            *reinterpret_cast<u16x8*>(reinterpret_cast<char*>(xhi) + byte) = h;
            *reinterpret_cast<u16x8*>(reinterpret_cast<char*>(xlo) + byte) = l;
        }
    }
    __syncthreads();

    f32x4 acc[4][2];
    #pragma unroll
    for (int m = 0; m < 4; ++m)
        #pragma unroll
        for (int nt = 0; nt < 2; ++nt)
            acc[m][nt] = (f32x4){0.f, 0.f, 0.f, 0.f};

    #pragma unroll
    for (int kk = 0; kk < 4; ++kk) {
        #pragma unroll
        for (int m = 0; m < 4; ++m) {
            int row  = m * 16 + (lane & 15);
            int koff = kk * 64 + (lane >> 4) * 16;
            int byte = row * 256 + (koff ^ ((row & 7) << 4));
            bf16x8 ahi = *reinterpret_cast<const bf16x8*>(reinterpret_cast<char*>(xhi) + byte);
            bf16x8 alo = *reinterpret_cast<const bf16x8*>(reinterpret_cast<char*>(xlo) + byte);
            #pragma unroll
            for (int nt = 0; nt < 2; ++nt) {
                acc[m][nt] = __builtin_amdgcn_mfma_f32_16x16x32_bf16(ahi, bhi[nt][kk], acc[m][nt], 0, 0, 0);
                acc[m][nt] = __builtin_amdgcn_mfma_f32_16x16x32_bf16(ahi, blo[nt][kk], acc[m][nt], 0, 0, 0);
                acc[m][nt] = __builtin_amdgcn_mfma_f32_16x16x32_bf16(alo, bhi[nt][kk], acc[m][nt], 0, 0, 0);
            }
        }
    }

    #pragma unroll
    for (int m = 0; m < 4; ++m) {
        int row = rbase + m * 16 + (lane >> 4) * 4;
        int col = w * 32 + (lane & 15);
        #pragma unroll
        for (int nt = 0; nt < 2; ++nt) {
            #pragma unroll
            for (int r = 0; r < 4; ++r) {
                if (row + r < N) {
                    float v = acc[m][nt][r];
                    if (SCALE_OUT) v *= dinv[row + r];
                    Hout[(size_t)(row + r) * NODE_F + col + nt * 16] = __float2half(v);
                }
            }
        }
    }
}

// ---- cooperative front-end ----------------------------------------------

struct FrontArgs {
    const int* dst; const int* src;
    int* degE; unsigned short* rank;
    int E, N, edge_blocks, gemm_tiles, nblk;
    const float* X; const unsigned short* WhiT; const unsigned short* WloT;
    __half* H;
    int* rsA; int* bsum; int* rsB; float* dinv;
    int* csr_src; int* counter;
};

__global__ __launch_bounds__(256) void frontend_kernel(FrontArgs a)
{
    cg::grid_group grid = cg::this_grid();
    __shared__ unsigned short xhi[64 * 128];
    __shared__ unsigned short xlo[64 * 128];
    const int G   = gridDim.x;
    const int bid = blockIdx.x;
    const int tid = threadIdx.x;
    int* t_sp = reinterpret_cast<int*>(xhi);   // aliased work-claim broadcast slot

    // ---- P0: deg_rank (first edge_blocks) then all blocks claim gemm1 tiles
    if (bid < a.edge_blocks) {
        int stride = a.edge_blocks * 256;
        for (int e = bid * 256 + tid; e < a.E; e += stride)
            a.rank[e] = (unsigned short)atomicAdd(&a.degE[a.dst[e]], 1);
    }
    for (;;) {
        __syncthreads();                         // prior tile's LDS reads done
        if (tid == 0) *t_sp = atomicAdd(a.counter, 1);
        __syncthreads();
        int t = *t_sp;
        __syncthreads();                         // all read t before staging overwrites
        if (t >= a.gemm_tiles) break;
        gemm_body<false, false>(a.X, nullptr, nullptr, a.WhiT, a.WloT, nullptr,
                                a.H, a.N, t, xhi, xlo);
    }
    grid.sync();

    // ---- P1: per-1024-chunk scan (nblk blocks)
    if (bid < a.nblk) {
        int* s = reinterpret_cast<int*>(xhi);
        const int idx = bid * 1024 + tid * 4;
        int v0 = (idx + 0 < a.N) ? a.degE[idx + 0] : 0;
        int v1 = (idx + 1 < a.N) ? a.degE[idx + 1] : 0;
        int v2 = (idx + 2 < a.N) ? a.degE[idx + 2] : 0;
        int v3 = (idx + 3 < a.N) ? a.degE[idx + 3] : 0;
        int t = v0 + v1 + v2 + v3;
        s[tid] = t;
        __syncthreads();
        #pragma unroll
        for (int off = 1; off < 256; off <<= 1) {
            int x = (tid >= off) ? s[tid - off] : 0;
            __syncthreads();
            s[tid] += x;
            __syncthreads();
        }
        int excl = s[tid] - t;
        if (idx + 0 < a.N) a.rsA[idx + 0] = excl;
        if (idx + 1 < a.N) a.rsA[idx + 1] = excl + v0;
        if (idx + 2 < a.N) a.rsA[idx + 2] = excl + v0 + v1;
        if (idx + 3 < a.N) a.rsA[idx + 3] = excl + v0 + v1 + v2;
        if (tid == 255) a.bsum[bid] = s[255];
    }
    grid.sync();

    // ---- P2: scan of block sums (block 0; nblk <= 128)
    if (bid == 0) {
        int* s = reinterpret_cast<int*>(xhi);
        int v = (tid < a.nblk) ? a.bsum[tid] : 0;
        if (tid < 128) s[tid] = v;
        __syncthreads();
        #pragma unroll
        for (int off = 1; off < 128; off <<= 1) {
            int x = (tid >= off && tid < 128) ? s[tid - off] : 0;
            __syncthreads();
            if (tid < 128) s[tid] += x;
            __syncthreads();
        }
        if (tid < a.nblk) a.bsum[tid] = s[tid] - v;
    }
    grid.sync();

    // ---- P3: finalize row_start -> rsB + dinv (reads rsA), and fill csr
    //          (fill computes positions from rsA + bsum: no dependence on rsB)
    {
        int stride = G * 256;
        for (int i = bid * 256 + tid; i < a.N; i += stride) {
            int rs = a.rsA[i] + a.bsum[i >> 10];
            a.rsB[i] = rs;
            a.dinv[i] = rsqrtf((float)a.degE[i] + 1.0f);
            if (i == a.N - 1) a.rsB[a.N] = rs + a.degE[i];
        }
        for (int e = bid * 256 + tid; e < a.E; e += stride) {
            int d = a.dst[e];
            a.csr_src[a.rsA[d] + a.bsum[d >> 10] + (int)a.rank[e]] = a.src[e];
        }
    }
}

// ---- gather core: quarter-wave per edge, 16B/lane; optional per-edge dinv

template<bool EDGE_SCALE>
__device__ __forceinline__ void gather_core(
    const __half* __restrict__ Hs, const int* __restrict__ csr_src,
    const int* __restrict__ row_start, const float* __restrict__ dinv,
    int node, int ql, int qi, float a[8])
{
    const char* Hb = reinterpret_cast<const char*>(Hs);
    #pragma unroll
    for (int j = 0; j < 8; ++j) a[j] = 0.f;
    if (qi == 0) {
        float ds = EDGE_SCALE ? dinv[node] : 1.0f;
        acc8_h(a, *reinterpret_cast<const uint4*>(Hb + ((size_t)node * 256 + ql * 16)), ds);
    }

    int i   = row_start[node];
    int end = row_start[node + 1];
    for (; i + 7 < end; i += 8) {
        int s0 = csr_src[i + qi];
        int s1 = csr_src[i + 4 + qi];
        float d0 = EDGE_SCALE ? dinv[s0] : 1.0f;
        float d1 = EDGE_SCALE ? dinv[s1] : 1.0f;
        uint4 v0 = *reinterpret_cast<const uint4*>(Hb + ((size_t)s0 * 256 + ql * 16));
        uint4 v1 = *reinterpret_cast<const uint4*>(Hb + ((size_t)s1 * 256 + ql * 16));
        acc8_h(a, v0, d0);
        acc8_h(a, v1, d1);
    }
    for (; i < end; i += 4) {
        if (i + qi < end) {
            int s = csr_src[i + qi];
            float ds = EDGE_SCALE ? dinv[s] : 1.0f;
            acc8_h(a, *reinterpret_cast<const uint4*>(Hb + ((size_t)s * 256 + ql * 16)), ds);
        }
    }
    #pragma unroll
    for (int j = 0; j < 8; ++j) {
        a[j] += __shfl_xor(a[j], 32);
        a[j] += __shfl_xor(a[j], 16);
    }
}

// ---- gather1: o = relu(b + dinv[d]*(sum dinv[s] H[s])) -> split bf16 ----

__global__ __launch_bounds__(256) void gather1_kernel(
    const __half* __restrict__ H, const int* __restrict__ csr_src,
    const int* __restrict__ row_start, const float* __restrict__ dinv,
    const float* __restrict__ b,
    unsigned short* __restrict__ Xhi, unsigned short* __restrict__ Xlo, int N)
{
    int node = (blockIdx.x * blockDim.x + threadIdx.x) >> 6;
    int lane = threadIdx.x & 63;
    int ql = lane & 15, qi = lane >> 4;
    if (node >= N) return;

    float a[8];
    gather_core<true>(H, csr_src, row_start, dinv, node, ql, qi, a);

    if (qi == 0) {
        const float dd = dinv[node];
        u16x8 h8, l8;
        #pragma unroll
        for (int j = 0; j < 8; ++j) {
            float r = fmaxf(b[ql * 8 + j] + dd * a[j], 0.f);
            unsigned short hi = bf16_rn(r);
            h8[j] = hi;
            l8[j] = bf16_rn(r - bf16_to_f(hi));
        }
        *reinterpret_cast<u16x8*>(Xhi + (size_t)node * NODE_F + ql * 8) = h8;
        *reinterpret_cast<u16x8*>(Xlo + (size_t)node * NODE_F + ql * 8) = l8;
    }
}

// ---- gather2 + FC (pre-scaled Hs): out = tanh(relu(b + dd*sum) @ Wfc + bfc)

__global__ __launch_bounds__(256) void gather2fc_kernel(
    const __half* __restrict__ Hs, const int* __restrict__ csr_src,
    const int* __restrict__ row_start, const float* __restrict__ dinv,
    const float* __restrict__ b, const float* __restrict__ Wfc,
    const float* __restrict__ bfc, float* __restrict__ out, int N)
{
    int node = (blockIdx.x * blockDim.x + threadIdx.x) >> 6;
    int lane = threadIdx.x & 63;
    int ql = lane & 15, qi = lane >> 4;
    if (node >= N) return;

    float a[8];
    gather_core<false>(Hs, csr_src, row_start, dinv, node, ql, qi, a);

    const float dd = dinv[node];
    float p0 = 0.f, p1 = 0.f, p2 = 0.f;
    #pragma unroll
    for (int j = 0; j < 8; ++j) {
        float r = fmaxf(b[ql * 8 + j] + dd * a[j], 0.f);
        const float* wr = Wfc + (size_t)(ql * 8 + j) * 3;
        p0 += r * wr[0]; p1 += r * wr[1]; p2 += r * wr[2];
    }
    #pragma unroll
    for (int off = 8; off > 0; off >>= 1) {
        p0 += __shfl_down(p0, off);
        p1 += __shfl_down(p1, off);
        p2 += __shfl_down(p2, off);
    }
    if (lane == 0) {
        out[(size_t)node * 3 + 0] = tanhf(p0 + bfc[0]);
        out[(size_t)node * 3 + 1] = tanhf(p1 + bfc[1]);
        out[(size_t)node * 3 + 2] = tanhf(p2 + bfc[2]);
    }
}

// ---- gemm2 (pre-split input, scaled epilogue) ---------------------------

__global__ __launch_bounds__(256) void gemm2_kernel(
    const unsigned short* __restrict__ Xhi_g, const unsigned short* __restrict__ Xlo_g,
    const unsigned short* __restrict__ WhiT, const unsigned short* __restrict__ WloT,
    const float* __restrict__ dinv, __half* __restrict__ Hs, int N)
{
    __shared__ unsigned short xhi[64 * 128];
    __shared__ unsigned short xlo[64 * 128];
    gemm_body<true, true>(nullptr, Xhi_g, Xlo_g, WhiT, WloT, dinv,
                          Hs, N, blockIdx.x, xhi, xlo);
}

extern "C" void kernel_launch(void* const* d_in, const int* in_sizes, int n_in,
                              void* d_out, int out_size, void* d_ws, size_t ws_size,
                              hipStream_t stream)
{
    const float* x    = (const float*)d_in[0];
    const int*   edge = (const int*)d_in[1];
    const float* W1   = (const float*)d_in[2];
    const float* b1   = (const float*)d_in[3];
    const float* W2   = (const float*)d_in[4];
    const float* b2   = (const float*)d_in[5];
    const float* Wfc  = (const float*)d_in[6];
    const float* bfc  = (const float*)d_in[7];
    float* out = (float*)d_out;

    const int N = in_sizes[0] / NODE_F;
    const int E = in_sizes[1] / 2;
    const int* src = edge;
    const int* dst = edge + E;

    char* ws = (char*)d_ws;
    size_t off = 0;
    auto alloc = [&](size_t bytes) {
        void* p = ws + off;
        off += (bytes + 511) & ~511ull;
        return p;
    };
    const int nblk = (N + 1023) / 1024;
    float* dinv      = (float*)alloc((size_t)N * 4);
    int*   degE      = (int*)  alloc((size_t)N * 4);
    unsigned short* rank = (unsigned short*)alloc((size_t)E * 2);
    int*   rsA       = (int*)  alloc((size_t)N * 4);
    int*   rsB       = (int*)  alloc((size_t)(N + 1) * 4);
    int*   bsum      = (int*)  alloc((size_t)nblk * 4);
    int*   csr_src   = (int*)  alloc((size_t)E * 4);
    int*   counter   = (int*)  alloc(4);
    unsigned short* WhiT = (unsigned short*)alloc(2 * 128 * 128 * 2);
    unsigned short* WloT = (unsigned short*)alloc(2 * 128 * 128 * 2);
    __half* H        = (__half*)alloc((size_t)N * NODE_F * 2);
    unsigned short* Xhi = (unsigned short*)alloc((size_t)N * NODE_F * 2);
    unsigned short* Xlo = (unsigned short*)alloc((size_t)N * NODE_F * 2);
    (void)ws_size; (void)n_in; (void)out_size;

    const int B = 256;
    const int gemm_grid   = (N + 63) / 64;
    const int gather_grid = (N + 3) / 4;

    // cooperative grid sizing
    int dev = 0;
    hipGetDevice(&dev);
    hipDeviceProp_t prop;
    hipGetDeviceProperties(&prop, dev);
    int bpc = 0;
    hipOccupancyMaxActiveBlocksPerMultiprocessor(&bpc, frontend_kernel, B, 0);
    if (bpc <= 0) bpc = 4;
    int G = prop.multiProcessorCount * bpc;
    if (G < 256) G = 256;
    int edge_blocks = G / 4;

    wconv_kernel<<<2, B, 0, stream>>>(W1, W2, WhiT, WloT, counter);
    hipMemsetAsync(degE, 0, (size_t)N * 4, stream);

    FrontArgs fa;
    fa.dst = dst; fa.src = src;
    fa.degE = degE; fa.rank = rank;
    fa.E = E; fa.N = N; fa.edge_blocks = edge_blocks;
    fa.gemm_tiles = gemm_grid; fa.nblk = nblk;
    fa.X = x; fa.WhiT = WhiT; fa.WloT = WloT;
    fa.H = H;
    fa.rsA = rsA; fa.bsum = bsum; fa.rsB = rsB; fa.dinv = dinv;
    fa.csr_src = csr_src; fa.counter = counter;
    void* kargs[] = {(void*)&fa};
    hipLaunchCooperativeKernel((void*)frontend_kernel, dim3(G), dim3(B), kargs, 0, stream);

    // layer-1 aggregate (unscaled H, per-edge dinv) -> relu -> split bf16
    gather1_kernel<<<gather_grid, B, 0, stream>>>(H, csr_src, rsB, dinv, b1, Xhi, Xlo, N);

    // layer-2 GEMM (pre-split input, scaled epilogue)
    gemm2_kernel<<<gemm_grid, B, 0, stream>>>(Xhi, Xlo, WhiT + 128 * 128, WloT + 128 * 128,
                                              dinv, H, N);

    // layer-2 aggregate + FC head
    gather2fc_kernel<<<gather_grid, B, 0, stream>>>(H, csr_src, rsB, dinv, b2,
                                                    Wfc, bfc, out, N);
}

// Round 11
// 340.460 us; speedup vs baseline: 1.2348x; 1.2348x over previous
//
#include <hip/hip_runtime.h>
#include <hip/hip_bf16.h>
#include <hip/hip_fp16.h>

// ResidualGNN: 2x GCNConv(128->128, relu) + FC(128->3, tanh), N=100000, E=1.6M, fp32.
// R10: fix R9's inter-block RAW race — aggemm2 wrote its output into the same H
//      buffer other blocks were reading (gather). Output now goes to separate H2.

#define NODE_F 128

typedef __attribute__((ext_vector_type(8))) short bf16x8;
typedef __attribute__((ext_vector_type(8))) unsigned short u16x8;
typedef __attribute__((ext_vector_type(4))) float f32x4;

__device__ inline unsigned short bf16_rn(float x) {
    unsigned u = __builtin_bit_cast(unsigned, x);
    unsigned r = (u + 0x7fffu + ((u >> 16) & 1u)) >> 16;
    return (unsigned short)r;
}
__device__ inline float bf16_to_f(unsigned short h) {
    unsigned u = (unsigned)h << 16;
    return __builtin_bit_cast(float, u);
}
__device__ inline void acc8_h(float a[8], uint4 v, float s) {
    unsigned vv[4] = {v.x, v.y, v.z, v.w};
    #pragma unroll
    for (int j = 0; j < 4; ++j) {
        float2 f = __half22float2(__builtin_bit_cast(__half2, vv[j]));
        a[2 * j]     += f.x * s;
        a[2 * j + 1] += f.y * s;
    }
}

// ---- W -> bf16 hi/lo, transposed to [n][k] ------------------------------

__global__ __launch_bounds__(256) void wconv_kernel(const float* __restrict__ W1,
                                                    const float* __restrict__ W2,
                                                    unsigned short* __restrict__ WhiT,
                                                    unsigned short* __restrict__ WloT)
{
    const float* W = blockIdx.x ? W2 : W1;
    unsigned short* hiT = WhiT + blockIdx.x * 128 * 128;
    unsigned short* loT = WloT + blockIdx.x * 128 * 128;
    int tid = threadIdx.x;
    for (int i = tid; i < 128 * 128; i += 256) {
        int k = i >> 7, n = i & 127;
        float x = W[i];
        unsigned short hi = bf16_rn(x);
        float lo = x - bf16_to_f(hi);
        hiT[n * 128 + k] = hi;
        loT[n * 128 + k] = bf16_rn(lo);
    }
}

// ---- scan ---------------------------------------------------------------

__global__ __launch_bounds__(256) void scan_block_kernel(
    const int* __restrict__ degE, int* __restrict__ rsA,
    int* __restrict__ bsum, int N)
{
    __shared__ int s[256];
    const int tid = threadIdx.x;
    const int idx = blockIdx.x * 1024 + tid * 4;
    int v0 = (idx + 0 < N) ? degE[idx + 0] : 0;
    int v1 = (idx + 1 < N) ? degE[idx + 1] : 0;
    int v2 = (idx + 2 < N) ? degE[idx + 2] : 0;
    int v3 = (idx + 3 < N) ? degE[idx + 3] : 0;
    int t = v0 + v1 + v2 + v3;
    s[tid] = t;
    __syncthreads();
    #pragma unroll
    for (int off = 1; off < 256; off <<= 1) {
        int x = (tid >= off) ? s[tid - off] : 0;
        __syncthreads();
        s[tid] += x;
        __syncthreads();
    }
    int excl = s[tid] - t;
    if (idx + 0 < N) rsA[idx + 0] = excl;
    if (idx + 1 < N) rsA[idx + 1] = excl + v0;
    if (idx + 2 < N) rsA[idx + 2] = excl + v0 + v1;
    if (idx + 3 < N) rsA[idx + 3] = excl + v0 + v1 + v2;
    if (tid == 255) bsum[blockIdx.x] = s[255];
}

__global__ __launch_bounds__(1024) void scan_tops_kernel(int* __restrict__ bsum, int nb) {
    __shared__ int s[1024];
    const int tid = threadIdx.x;
    int v = (tid < nb) ? bsum[tid] : 0;
    s[tid] = v;
    __syncthreads();
    #pragma unroll
    for (int off = 1; off < 1024; off <<= 1) {
        int x = (tid >= off) ? s[tid - off] : 0;
        __syncthreads();
        s[tid] += x;
        __syncthreads();
    }
    if (tid < nb) bsum[tid] = s[tid] - v;
}

// ---- finish || fill (both read rsA+bsum; no cross-dependency) -----------

__global__ __launch_bounds__(256) void finish_fill_kernel(
    const int* __restrict__ src, const int* __restrict__ dst,
    const unsigned short* __restrict__ rank,
    const int* __restrict__ rsA, const int* __restrict__ bsum,
    int* __restrict__ rsB, float* __restrict__ dinv,
    const int* __restrict__ degE, int* __restrict__ csr_src,
    int E, int N, int fill_blocks)
{
    if ((int)blockIdx.x < fill_blocks) {
        int e = blockIdx.x * 256 + threadIdx.x;
        if (e < E) {
            int d = dst[e];
            csr_src[rsA[d] + bsum[d >> 10] + (int)rank[e]] = src[e];
        }
    } else {
        int i = (blockIdx.x - fill_blocks) * 256 + threadIdx.x;
        if (i < N) {
            int rs = rsA[i] + bsum[i >> 10];
            rsB[i] = rs;
            dinv[i] = rsqrtf((float)degE[i] + 1.0f);
            if (i == N - 1) rsB[N] = rs + degE[i];
        }
    }
}

// ---- GEMM compute core: B-frag preload + MFMA + epilogue ----------------

template<bool SCALE_OUT>
__device__ __forceinline__ void gemm_compute(
    const unsigned short* __restrict__ WhiT, const unsigned short* __restrict__ WloT,
    const float* __restrict__ dinv, __half* __restrict__ Hout, int N, int rbase,
    unsigned short* xhi, unsigned short* xlo)
{
    const int tid  = threadIdx.x;
    const int lane = tid & 63;
    const int w    = tid >> 6;

    bf16x8 bhi[2][4], blo[2][4];
    {
        int n0   = w * 32 + (lane & 15);
        int koct = (lane >> 4) * 8;
        #pragma unroll
        for (int nt = 0; nt < 2; ++nt) {
            #pragma unroll
            for (int kk = 0; kk < 4; ++kk) {
                size_t o = (size_t)(n0 + nt * 16) * 128 + kk * 32 + koct;
                bhi[nt][kk] = *reinterpret_cast<const bf16x8*>(WhiT + o);
                blo[nt][kk] = *reinterpret_cast<const bf16x8*>(WloT + o);
            }
        }
    }

    f32x4 acc[4][2];
    #pragma unroll
    for (int m = 0; m < 4; ++m)
        #pragma unroll
        for (int nt = 0; nt < 2; ++nt)
            acc[m][nt] = (f32x4){0.f, 0.f, 0.f, 0.f};

    #pragma unroll
    for (int kk = 0; kk < 4; ++kk) {
        #pragma unroll
        for (int m = 0; m < 4; ++m) {
            int row  = m * 16 + (lane & 15);
            int koff = kk * 64 + (lane >> 4) * 16;
            int byte = row * 256 + (koff ^ ((row & 7) << 4));
            bf16x8 ahi = *reinterpret_cast<const bf16x8*>(reinterpret_cast<char*>(xhi) + byte);
            bf16x8 alo = *reinterpret_cast<const bf16x8*>(reinterpret_cast<char*>(xlo) + byte);
            #pragma unroll
            for (int nt = 0; nt < 2; ++nt) {
                acc[m][nt] = __builtin_amdgcn_mfma_f32_16x16x32_bf16(ahi, bhi[nt][kk], acc[m][nt], 0, 0, 0);
                acc[m][nt] = __builtin_amdgcn_mfma_f32_16x16x32_bf16(ahi, blo[nt][kk], acc[m][nt], 0, 0, 0);
                acc[m][nt] = __builtin_amdgcn_mfma_f32_16x16x32_bf16(alo, bhi[nt][kk], acc[m][nt], 0, 0, 0);
            }
        }
    }

    #pragma unroll
    for (int m = 0; m < 4; ++m) {
        int row = rbase + m * 16 + (lane >> 4) * 4;
        int col = w * 32 + (lane & 15);
        #pragma unroll
        for (int nt = 0; nt < 2; ++nt) {
            #pragma unroll
            for (int r = 0; r < 4; ++r) {
                if (row + r < N) {
                    float v = acc[m][nt][r];
                    if (SCALE_OUT) v *= dinv[row + r];
                    Hout[(size_t)(row + r) * NODE_F + col + nt * 16] = __float2half(v);
                }
            }
        }
    }
}

// ---- gemm1 body: fp32 input, convert+split staging ----------------------

__device__ __forceinline__ void gemm1_body(
    const float* __restrict__ Xf,
    const unsigned short* __restrict__ WhiT, const unsigned short* __restrict__ WloT,
    __half* __restrict__ Hout, int N, int bid,
    unsigned short* xhi, unsigned short* xlo)
{
    const int tid   = threadIdx.x;
    const int rbase = bid * 64;

    #pragma unroll
    for (int it = 0; it < 8; ++it) {
        int f   = it * 256 + tid;
        int row = f >> 5;
        int k4  = f & 31;
        float4 v = make_float4(0.f, 0.f, 0.f, 0.f);
        if (rbase + row < N)
            v = *reinterpret_cast<const float4*>(Xf + (size_t)(rbase + row) * NODE_F + k4 * 4);
        float xs[4] = {v.x, v.y, v.z, v.w};
        ushort4 h4, l4;
        unsigned short* hp = &h4.x;
        unsigned short* lp = &l4.x;
        #pragma unroll
        for (int j = 0; j < 4; ++j) {
            unsigned short hi = bf16_rn(xs[j]);
            hp[j] = hi;
            lp[j] = bf16_rn(xs[j] - bf16_to_f(hi));
        }
        int byte = row * 256 + ((k4 * 8) ^ ((row & 7) << 4));
        *reinterpret_cast<ushort4*>(reinterpret_cast<char*>(xhi) + byte) = h4;
        *reinterpret_cast<ushort4*>(reinterpret_cast<char*>(xlo) + byte) = l4;
    }
    __syncthreads();
    gemm_compute<false>(WhiT, WloT, nullptr, Hout, N, rbase, xhi, xlo);
}

// ---- gemm1 + deg_rank as 1:4 modulo-interleaved block roles -------------

__global__ __launch_bounds__(256) void gemm1deg_kernel(
    const int* __restrict__ dst, int* __restrict__ degE,
    unsigned short* __restrict__ rank, int E,
    int edge_blocks, int gemm_blocks,
    const float* __restrict__ X, const unsigned short* __restrict__ WhiT,
    const unsigned short* __restrict__ WloT, __half* __restrict__ H, int N)
{
    __shared__ unsigned short xhi[64 * 128];
    __shared__ unsigned short xlo[64 * 128];
    int q = blockIdx.x / 5, r = blockIdx.x % 5;
    if (r == 4) {
        int stride = edge_blocks * 256;
        for (int e = q * 256 + threadIdx.x; e < E; e += stride)
            rank[e] = (unsigned short)atomicAdd(&degE[dst[e]], 1);
    } else {
        int gid = q * 4 + r;
        if (gid < gemm_blocks)
            gemm1_body(X, WhiT, WloT, H, N, gid, xhi, xlo);
    }
}

// ---- gather core: quarter-wave per edge, 16B/lane; optional per-edge dinv

template<bool EDGE_SCALE>
__device__ __forceinline__ void gather_core(
    const __half* __restrict__ Hs, const int* __restrict__ csr_src,
    const int* __restrict__ row_start, const float* __restrict__ dinv,
    int node, int ql, int qi, float a[8])
{
    const char* Hb = reinterpret_cast<const char*>(Hs);
    #pragma unroll
    for (int j = 0; j < 8; ++j) a[j] = 0.f;
    if (qi == 0) {
        float ds = EDGE_SCALE ? dinv[node] : 1.0f;
        acc8_h(a, *reinterpret_cast<const uint4*>(Hb + ((size_t)node * 256 + ql * 16)), ds);
    }

    int i   = row_start[node];
    int end = row_start[node + 1];
    for (; i + 7 < end; i += 8) {
        int s0 = csr_src[i + qi];
        int s1 = csr_src[i + 4 + qi];
        float d0 = EDGE_SCALE ? dinv[s0] : 1.0f;
        float d1 = EDGE_SCALE ? dinv[s1] : 1.0f;
        uint4 v0 = *reinterpret_cast<const uint4*>(Hb + ((size_t)s0 * 256 + ql * 16));
        uint4 v1 = *reinterpret_cast<const uint4*>(Hb + ((size_t)s1 * 256 + ql * 16));
        acc8_h(a, v0, d0);
        acc8_h(a, v1, d1);
    }
    for (; i < end; i += 4) {
        if (i + qi < end) {
            int s = csr_src[i + qi];
            float ds = EDGE_SCALE ? dinv[s] : 1.0f;
            acc8_h(a, *reinterpret_cast<const uint4*>(Hb + ((size_t)s * 256 + ql * 16)), ds);
        }
    }
    #pragma unroll
    for (int j = 0; j < 8; ++j) {
        a[j] += __shfl_xor(a[j], 32);
        a[j] += __shfl_xor(a[j], 16);
    }
}

// ---- aggemm2: layer-1 aggregate straight into LDS, then layer-2 GEMM ----
// block owns 64 output rows; wave w aggregates nodes rbase+w*16 .. +15.
// Reads H (layer-1), writes H2 (separate buffer — no inter-block race).

__global__ __launch_bounds__(256) void aggemm2_kernel(
    const __half* __restrict__ H, const int* __restrict__ csr_src,
    const int* __restrict__ row_start, const float* __restrict__ dinv,
    const float* __restrict__ b1,
    const unsigned short* __restrict__ WhiT, const unsigned short* __restrict__ WloT,
    __half* __restrict__ H2, int N)
{
    __shared__ unsigned short xhi[64 * 128];
    __shared__ unsigned short xlo[64 * 128];
    const int tid  = threadIdx.x;
    const int lane = tid & 63;
    const int w    = tid >> 6;
    const int ql   = lane & 15, qi = lane >> 4;
    const int rbase = blockIdx.x * 64;

    float bv[8];
    {
        float4 b0 = *reinterpret_cast<const float4*>(b1 + ql * 8);
        float4 b4 = *reinterpret_cast<const float4*>(b1 + ql * 8 + 4);
        bv[0] = b0.x; bv[1] = b0.y; bv[2] = b0.z; bv[3] = b0.w;
        bv[4] = b4.x; bv[5] = b4.y; bv[6] = b4.z; bv[7] = b4.w;
    }

    for (int r16 = 0; r16 < 16; ++r16) {
        int row  = w * 16 + r16;
        int node = rbase + row;
        float a[8];
        if (node < N)
            gather_core<true>(H, csr_src, row_start, dinv, node, ql, qi, a);
        if (qi == 0) {
            u16x8 h8 = {0, 0, 0, 0, 0, 0, 0, 0};
            u16x8 l8 = {0, 0, 0, 0, 0, 0, 0, 0};
            if (node < N) {
                float dd = dinv[node];
                #pragma unroll
                for (int j = 0; j < 8; ++j) {
                    float r = fmaxf(bv[j] + dd * a[j], 0.f);
                    unsigned short hi = bf16_rn(r);
                    h8[j] = hi;
                    l8[j] = bf16_rn(r - bf16_to_f(hi));
                }
            }
            int byte = row * 256 + ((ql * 16) ^ ((row & 7) << 4));
            *reinterpret_cast<u16x8*>(reinterpret_cast<char*>(xhi) + byte) = h8;
            *reinterpret_cast<u16x8*>(reinterpret_cast<char*>(xlo) + byte) = l8;
        }
    }
    __syncthreads();
    gemm_compute<true>(WhiT, WloT, dinv, H2, N, rbase, xhi, xlo);
}

// ---- gather2 + FC (pre-scaled Hs): out = tanh(relu(b + dd*sum) @ Wfc + bfc)

__global__ __launch_bounds__(256) void gather2fc_kernel(
    const __half* __restrict__ Hs, const int* __restrict__ csr_src,
    const int* __restrict__ row_start, const float* __restrict__ dinv,
    const float* __restrict__ b, const float* __restrict__ Wfc,
    const float* __restrict__ bfc, float* __restrict__ out, int N)
{
    int node = (blockIdx.x * blockDim.x + threadIdx.x) >> 6;
    int lane = threadIdx.x & 63;
    int ql = lane & 15, qi = lane >> 4;
    if (node >= N) return;

    float a[8];
    gather_core<false>(Hs, csr_src, row_start, dinv, node, ql, qi, a);

    const float dd = dinv[node];
    float p0 = 0.f, p1 = 0.f, p2 = 0.f;
    #pragma unroll
    for (int j = 0; j < 8; ++j) {
        float r = fmaxf(b[ql * 8 + j] + dd * a[j], 0.f);
        const float* wr = Wfc + (size_t)(ql * 8 + j) * 3;
        p0 += r * wr[0]; p1 += r * wr[1]; p2 += r * wr[2];
    }
    #pragma unroll
    for (int off = 8; off > 0; off >>= 1) {
        p0 += __shfl_down(p0, off);
        p1 += __shfl_down(p1, off);
        p2 += __shfl_down(p2, off);
    }
    if (lane == 0) {
        out[(size_t)node * 3 + 0] = tanhf(p0 + bfc[0]);
        out[(size_t)node * 3 + 1] = tanhf(p1 + bfc[1]);
        out[(size_t)node * 3 + 2] = tanhf(p2 + bfc[2]);
    }
}

extern "C" void kernel_launch(void* const* d_in, const int* in_sizes, int n_in,
                              void* d_out, int out_size, void* d_ws, size_t ws_size,
                              hipStream_t stream)
{
    const float* x    = (const float*)d_in[0];
    const int*   edge = (const int*)d_in[1];
    const float* W1   = (const float*)d_in[2];
    const float* b1   = (const float*)d_in[3];
    const float* W2   = (const float*)d_in[4];
    const float* b2   = (const float*)d_in[5];
    const float* Wfc  = (const float*)d_in[6];
    const float* bfc  = (const float*)d_in[7];
    float* out = (float*)d_out;

    const int N = in_sizes[0] / NODE_F;
    const int E = in_sizes[1] / 2;
    const int* src = edge;
    const int* dst = edge + E;

    char* ws = (char*)d_ws;
    size_t off = 0;
    auto alloc = [&](size_t bytes) {
        void* p = ws + off;
        off += (bytes + 511) & ~511ull;
        return p;
    };
    const int nblk = (N + 1023) / 1024;
    float* dinv      = (float*)alloc((size_t)N * 4);
    int*   degE      = (int*)  alloc((size_t)N * 4);
    unsigned short* rank = (unsigned short*)alloc((size_t)E * 2);
    int*   rsA       = (int*)  alloc((size_t)N * 4);
    int*   rsB       = (int*)  alloc((size_t)(N + 1) * 4);
    int*   bsum      = (int*)  alloc((size_t)nblk * 4);
    int*   csr_src   = (int*)  alloc((size_t)E * 4);
    unsigned short* WhiT = (unsigned short*)alloc(2 * 128 * 128 * 2);
    unsigned short* WloT = (unsigned short*)alloc(2 * 128 * 128 * 2);
    __half* H        = (__half*)alloc((size_t)N * NODE_F * 2);
    __half* H2       = (__half*)alloc((size_t)N * NODE_F * 2);
    (void)ws_size; (void)n_in; (void)out_size;

    const int B = 256;
    const int gemm_grid   = (N + 63) / 64;
    const int gather_grid = (N + 3) / 4;
    const int fill_blocks = (E + B - 1) / B;
    const int fin_blocks  = (N + B - 1) / B;

    // 1:4 interleave for gemm1deg
    const int edge_blocks  = (gemm_grid + 3) / 4;
    const int total_blocks = gemm_grid + edge_blocks + 4;

    wconv_kernel<<<2, B, 0, stream>>>(W1, W2, WhiT, WloT);
    hipMemsetAsync(degE, 0, (size_t)N * 4, stream);

    // gemm1 (unscaled H) with deg_rank as interleaved block roles
    gemm1deg_kernel<<<total_blocks, B, 0, stream>>>(
        dst, degE, rank, E, edge_blocks, gemm_grid, x, WhiT, WloT, H, N);

    scan_block_kernel<<<nblk, B, 0, stream>>>(degE, rsA, bsum, N);
    scan_tops_kernel<<<1, 1024, 0, stream>>>(bsum, nblk);

    // [fill csr || finalize row_start + dinv]
    finish_fill_kernel<<<fill_blocks + fin_blocks, B, 0, stream>>>(
        src, dst, rank, rsA, bsum, rsB, dinv, degE, csr_src, E, N, fill_blocks);

    // layer-1 aggregate (per-edge dinv) + layer-2 GEMM fused -> H2
    aggemm2_kernel<<<gemm_grid, B, 0, stream>>>(
        H, csr_src, rsB, dinv, b1, WhiT + 128 * 128, WloT + 128 * 128, H2, N);

    // layer-2 aggregate + FC head
    gather2fc_kernel<<<gather_grid, B, 0, stream>>>(H2, csr_src, rsB, dinv, b2,
                                                    Wfc, bfc, out, N);
}

// Round 12
// 301.154 us; speedup vs baseline: 1.3960x; 1.1305x over previous
//
#include <hip/hip_runtime.h>
#include <hip/hip_bf16.h>
#include <hip/hip_fp16.h>

// ResidualGNN: 2x GCNConv(128->128, relu) + FC(128->3, tanh), N=100000, E=1.6M, fp32.
// R11: revert aggemm2 fusion (occupancy loss, 139 vs 105 split). Split gather1+gemm2
//      restored; gather1 now emits plain fp16 activations (25MB not 51MB split pair);
//      gemm2 splits fp16->bf16 hi/lo in-register during LDS staging.

#define NODE_F 128

typedef __attribute__((ext_vector_type(8))) short bf16x8;
typedef __attribute__((ext_vector_type(8))) unsigned short u16x8;
typedef __attribute__((ext_vector_type(4))) float f32x4;

__device__ inline unsigned short bf16_rn(float x) {
    unsigned u = __builtin_bit_cast(unsigned, x);
    unsigned r = (u + 0x7fffu + ((u >> 16) & 1u)) >> 16;
    return (unsigned short)r;
}
__device__ inline float bf16_to_f(unsigned short h) {
    unsigned u = (unsigned)h << 16;
    return __builtin_bit_cast(float, u);
}
__device__ inline void acc8_h(float a[8], uint4 v, float s) {
    unsigned vv[4] = {v.x, v.y, v.z, v.w};
    #pragma unroll
    for (int j = 0; j < 4; ++j) {
        float2 f = __half22float2(__builtin_bit_cast(__half2, vv[j]));
        a[2 * j]     += f.x * s;
        a[2 * j + 1] += f.y * s;
    }
}

// ---- W -> bf16 hi/lo, transposed to [n][k] ------------------------------

__global__ __launch_bounds__(256) void wconv_kernel(const float* __restrict__ W1,
                                                    const float* __restrict__ W2,
                                                    unsigned short* __restrict__ WhiT,
                                                    unsigned short* __restrict__ WloT)
{
    const float* W = blockIdx.x ? W2 : W1;
    unsigned short* hiT = WhiT + blockIdx.x * 128 * 128;
    unsigned short* loT = WloT + blockIdx.x * 128 * 128;
    int tid = threadIdx.x;
    for (int i = tid; i < 128 * 128; i += 256) {
        int k = i >> 7, n = i & 127;
        float x = W[i];
        unsigned short hi = bf16_rn(x);
        float lo = x - bf16_to_f(hi);
        hiT[n * 128 + k] = hi;
        loT[n * 128 + k] = bf16_rn(lo);
    }
}

// ---- scan ---------------------------------------------------------------

__global__ __launch_bounds__(256) void scan_block_kernel(
    const int* __restrict__ degE, int* __restrict__ rsA,
    int* __restrict__ bsum, int N)
{
    __shared__ int s[256];
    const int tid = threadIdx.x;
    const int idx = blockIdx.x * 1024 + tid * 4;
    int v0 = (idx + 0 < N) ? degE[idx + 0] : 0;
    int v1 = (idx + 1 < N) ? degE[idx + 1] : 0;
    int v2 = (idx + 2 < N) ? degE[idx + 2] : 0;
    int v3 = (idx + 3 < N) ? degE[idx + 3] : 0;
    int t = v0 + v1 + v2 + v3;
    s[tid] = t;
    __syncthreads();
    #pragma unroll
    for (int off = 1; off < 256; off <<= 1) {
        int x = (tid >= off) ? s[tid - off] : 0;
        __syncthreads();
        s[tid] += x;
        __syncthreads();
    }
    int excl = s[tid] - t;
    if (idx + 0 < N) rsA[idx + 0] = excl;
    if (idx + 1 < N) rsA[idx + 1] = excl + v0;
    if (idx + 2 < N) rsA[idx + 2] = excl + v0 + v1;
    if (idx + 3 < N) rsA[idx + 3] = excl + v0 + v1 + v2;
    if (tid == 255) bsum[blockIdx.x] = s[255];
}

__global__ __launch_bounds__(1024) void scan_tops_kernel(int* __restrict__ bsum, int nb) {
    __shared__ int s[1024];
    const int tid = threadIdx.x;
    int v = (tid < nb) ? bsum[tid] : 0;
    s[tid] = v;
    __syncthreads();
    #pragma unroll
    for (int off = 1; off < 1024; off <<= 1) {
        int x = (tid >= off) ? s[tid - off] : 0;
        __syncthreads();
        s[tid] += x;
        __syncthreads();
    }
    if (tid < nb) bsum[tid] = s[tid] - v;
}

// ---- finish || fill (both read rsA+bsum; no cross-dependency) -----------

__global__ __launch_bounds__(256) void finish_fill_kernel(
    const int* __restrict__ src, const int* __restrict__ dst,
    const unsigned short* __restrict__ rank,
    const int* __restrict__ rsA, const int* __restrict__ bsum,
    int* __restrict__ rsB, float* __restrict__ dinv,
    const int* __restrict__ degE, int* __restrict__ csr_src,
    int E, int N, int fill_blocks)
{
    if ((int)blockIdx.x < fill_blocks) {
        int e = blockIdx.x * 256 + threadIdx.x;
        if (e < E) {
            int d = dst[e];
            csr_src[rsA[d] + bsum[d >> 10] + (int)rank[e]] = src[e];
        }
    } else {
        int i = (blockIdx.x - fill_blocks) * 256 + threadIdx.x;
        if (i < N) {
            int rs = rsA[i] + bsum[i >> 10];
            rsB[i] = rs;
            dinv[i] = rsqrtf((float)degE[i] + 1.0f);
            if (i == N - 1) rsB[N] = rs + degE[i];
        }
    }
}

// ---- GEMM compute core: B-frag preload + MFMA + epilogue ----------------

template<bool SCALE_OUT>
__device__ __forceinline__ void gemm_compute(
    const unsigned short* __restrict__ WhiT, const unsigned short* __restrict__ WloT,
    const float* __restrict__ dinv, __half* __restrict__ Hout, int N, int rbase,
    unsigned short* xhi, unsigned short* xlo)
{
    const int tid  = threadIdx.x;
    const int lane = tid & 63;
    const int w    = tid >> 6;

    bf16x8 bhi[2][4], blo[2][4];
    {
        int n0   = w * 32 + (lane & 15);
        int koct = (lane >> 4) * 8;
        #pragma unroll
        for (int nt = 0; nt < 2; ++nt) {
            #pragma unroll
            for (int kk = 0; kk < 4; ++kk) {
                size_t o = (size_t)(n0 + nt * 16) * 128 + kk * 32 + koct;
                bhi[nt][kk] = *reinterpret_cast<const bf16x8*>(WhiT + o);
                blo[nt][kk] = *reinterpret_cast<const bf16x8*>(WloT + o);
            }
        }
    }

    f32x4 acc[4][2];
    #pragma unroll
    for (int m = 0; m < 4; ++m)
        #pragma unroll
        for (int nt = 0; nt < 2; ++nt)
            acc[m][nt] = (f32x4){0.f, 0.f, 0.f, 0.f};

    #pragma unroll
    for (int kk = 0; kk < 4; ++kk) {
        #pragma unroll
        for (int m = 0; m < 4; ++m) {
            int row  = m * 16 + (lane & 15);
            int koff = kk * 64 + (lane >> 4) * 16;
            int byte = row * 256 + (koff ^ ((row & 7) << 4));
            bf16x8 ahi = *reinterpret_cast<const bf16x8*>(reinterpret_cast<char*>(xhi) + byte);
            bf16x8 alo = *reinterpret_cast<const bf16x8*>(reinterpret_cast<char*>(xlo) + byte);
            #pragma unroll
            for (int nt = 0; nt < 2; ++nt) {
                acc[m][nt] = __builtin_amdgcn_mfma_f32_16x16x32_bf16(ahi, bhi[nt][kk], acc[m][nt], 0, 0, 0);
                acc[m][nt] = __builtin_amdgcn_mfma_f32_16x16x32_bf16(ahi, blo[nt][kk], acc[m][nt], 0, 0, 0);
                acc[m][nt] = __builtin_amdgcn_mfma_f32_16x16x32_bf16(alo, bhi[nt][kk], acc[m][nt], 0, 0, 0);
            }
        }
    }

    #pragma unroll
    for (int m = 0; m < 4; ++m) {
        int row = rbase + m * 16 + (lane >> 4) * 4;
        int col = w * 32 + (lane & 15);
        #pragma unroll
        for (int nt = 0; nt < 2; ++nt) {
            #pragma unroll
            for (int r = 0; r < 4; ++r) {
                if (row + r < N) {
                    float v = acc[m][nt][r];
                    if (SCALE_OUT) v *= dinv[row + r];
                    Hout[(size_t)(row + r) * NODE_F + col + nt * 16] = __float2half(v);
                }
            }
        }
    }
}

// ---- gemm1 body: fp32 input, convert+split staging ----------------------

__device__ __forceinline__ void gemm1_body(
    const float* __restrict__ Xf,
    const unsigned short* __restrict__ WhiT, const unsigned short* __restrict__ WloT,
    __half* __restrict__ Hout, int N, int bid,
    unsigned short* xhi, unsigned short* xlo)
{
    const int tid   = threadIdx.x;
    const int rbase = bid * 64;

    #pragma unroll
    for (int it = 0; it < 8; ++it) {
        int f   = it * 256 + tid;
        int row = f >> 5;
        int k4  = f & 31;
        float4 v = make_float4(0.f, 0.f, 0.f, 0.f);
        if (rbase + row < N)
            v = *reinterpret_cast<const float4*>(Xf + (size_t)(rbase + row) * NODE_F + k4 * 4);
        float xs[4] = {v.x, v.y, v.z, v.w};
        ushort4 h4, l4;
        unsigned short* hp = &h4.x;
        unsigned short* lp = &l4.x;
        #pragma unroll
        for (int j = 0; j < 4; ++j) {
            unsigned short hi = bf16_rn(xs[j]);
            hp[j] = hi;
            lp[j] = bf16_rn(xs[j] - bf16_to_f(hi));
        }
        int byte = row * 256 + ((k4 * 8) ^ ((row & 7) << 4));
        *reinterpret_cast<ushort4*>(reinterpret_cast<char*>(xhi) + byte) = h4;
        *reinterpret_cast<ushort4*>(reinterpret_cast<char*>(xlo) + byte) = l4;
    }
    __syncthreads();
    gemm_compute<false>(WhiT, WloT, nullptr, Hout, N, rbase, xhi, xlo);
}

// ---- gemm1 + deg_rank as 1:4 modulo-interleaved block roles -------------

__global__ __launch_bounds__(256) void gemm1deg_kernel(
    const int* __restrict__ dst, int* __restrict__ degE,
    unsigned short* __restrict__ rank, int E,
    int edge_blocks, int gemm_blocks,
    const float* __restrict__ X, const unsigned short* __restrict__ WhiT,
    const unsigned short* __restrict__ WloT, __half* __restrict__ H, int N)
{
    __shared__ unsigned short xhi[64 * 128];
    __shared__ unsigned short xlo[64 * 128];
    int q = blockIdx.x / 5, r = blockIdx.x % 5;
    if (r == 4) {
        int stride = edge_blocks * 256;
        for (int e = q * 256 + threadIdx.x; e < E; e += stride)
            rank[e] = (unsigned short)atomicAdd(&degE[dst[e]], 1);
    } else {
        int gid = q * 4 + r;
        if (gid < gemm_blocks)
            gemm1_body(X, WhiT, WloT, H, N, gid, xhi, xlo);
    }
}

// ---- gather core: quarter-wave per edge, 16B/lane; optional per-edge dinv

template<bool EDGE_SCALE>
__device__ __forceinline__ void gather_core(
    const __half* __restrict__ Hs, const int* __restrict__ csr_src,
    const int* __restrict__ row_start, const float* __restrict__ dinv,
    int node, int ql, int qi, float a[8])
{
    const char* Hb = reinterpret_cast<const char*>(Hs);
    #pragma unroll
    for (int j = 0; j < 8; ++j) a[j] = 0.f;
    if (qi == 0) {
        float ds = EDGE_SCALE ? dinv[node] : 1.0f;
        acc8_h(a, *reinterpret_cast<const uint4*>(Hb + ((size_t)node * 256 + ql * 16)), ds);
    }

    int i   = row_start[node];
    int end = row_start[node + 1];
    for (; i + 7 < end; i += 8) {
        int s0 = csr_src[i + qi];
        int s1 = csr_src[i + 4 + qi];
        float d0 = EDGE_SCALE ? dinv[s0] : 1.0f;
        float d1 = EDGE_SCALE ? dinv[s1] : 1.0f;
        uint4 v0 = *reinterpret_cast<const uint4*>(Hb + ((size_t)s0 * 256 + ql * 16));
        uint4 v1 = *reinterpret_cast<const uint4*>(Hb + ((size_t)s1 * 256 + ql * 16));
        acc8_h(a, v0, d0);
        acc8_h(a, v1, d1);
    }
    for (; i < end; i += 4) {
        if (i + qi < end) {
            int s = csr_src[i + qi];
            float ds = EDGE_SCALE ? dinv[s] : 1.0f;
            acc8_h(a, *reinterpret_cast<const uint4*>(Hb + ((size_t)s * 256 + ql * 16)), ds);
        }
    }
    #pragma unroll
    for (int j = 0; j < 8; ++j) {
        a[j] += __shfl_xor(a[j], 32);
        a[j] += __shfl_xor(a[j], 16);
    }
}

// ---- gather1: A1 = relu(b + dinv[d]*(sum dinv[s] H[s])) as fp16 ---------

__global__ __launch_bounds__(256) void gather1_kernel(
    const __half* __restrict__ H, const int* __restrict__ csr_src,
    const int* __restrict__ row_start, const float* __restrict__ dinv,
    const float* __restrict__ b, __half* __restrict__ A1, int N)
{
    int node = (blockIdx.x * blockDim.x + threadIdx.x) >> 6;
    int lane = threadIdx.x & 63;
    int ql = lane & 15, qi = lane >> 4;
    if (node >= N) return;

    float a[8];
    gather_core<true>(H, csr_src, row_start, dinv, node, ql, qi, a);

    if (qi == 0) {
        const float dd = dinv[node];
        u16x8 o;
        #pragma unroll
        for (int j = 0; j < 8; ++j) {
            float r = fmaxf(b[ql * 8 + j] + dd * a[j], 0.f);
            o[j] = __builtin_bit_cast(unsigned short, __float2half(r));
        }
        *reinterpret_cast<u16x8*>(reinterpret_cast<char*>(A1) + ((size_t)node * 256 + ql * 16)) = o;
    }
}

// ---- gemm2: fp16 input, split fp16->bf16 hi/lo during staging -----------

__global__ __launch_bounds__(256) void gemm2_kernel(
    const __half* __restrict__ A1,
    const unsigned short* __restrict__ WhiT, const unsigned short* __restrict__ WloT,
    const float* __restrict__ dinv, __half* __restrict__ Hs, int N)
{
    __shared__ unsigned short xhi[64 * 128];
    __shared__ unsigned short xlo[64 * 128];
    const int tid   = threadIdx.x;
    const int rbase = blockIdx.x * 64;

    #pragma unroll
    for (int it = 0; it < 4; ++it) {
        int idx = it * 256 + tid;          // 8-half units; 1024 total
        int row = idx >> 4;
        int k8  = idx & 15;
        u16x8 h = {0, 0, 0, 0, 0, 0, 0, 0};
        u16x8 l = {0, 0, 0, 0, 0, 0, 0, 0};
        if (rbase + row < N) {
            u16x8 v = *reinterpret_cast<const u16x8*>(
                reinterpret_cast<const char*>(A1) + ((size_t)(rbase + row) * 256 + k8 * 16));
            #pragma unroll
            for (int j = 0; j < 8; ++j) {
                float f = __half2float(__builtin_bit_cast(__half, (unsigned short)v[j]));
                unsigned short hi = bf16_rn(f);
                h[j] = hi;
                l[j] = bf16_rn(f - bf16_to_f(hi));
            }
        }
        int byte = row * 256 + ((k8 * 16) ^ ((row & 7) << 4));
        *reinterpret_cast<u16x8*>(reinterpret_cast<char*>(xhi) + byte) = h;
        *reinterpret_cast<u16x8*>(reinterpret_cast<char*>(xlo) + byte) = l;
    }
    __syncthreads();
    gemm_compute<true>(WhiT, WloT, dinv, Hs, N, rbase, xhi, xlo);
}

// ---- gather2 + FC (pre-scaled Hs): out = tanh(relu(b + dd*sum) @ Wfc + bfc)

__global__ __launch_bounds__(256) void gather2fc_kernel(
    const __half* __restrict__ Hs, const int* __restrict__ csr_src,
    const int* __restrict__ row_start, const float* __restrict__ dinv,
    const float* __restrict__ b, const float* __restrict__ Wfc,
    const float* __restrict__ bfc, float* __restrict__ out, int N)
{
    int node = (blockIdx.x * blockDim.x + threadIdx.x) >> 6;
    int lane = threadIdx.x & 63;
    int ql = lane & 15, qi = lane >> 4;
    if (node >= N) return;

    float a[8];
    gather_core<false>(Hs, csr_src, row_start, dinv, node, ql, qi, a);

    const float dd = dinv[node];
    float p0 = 0.f, p1 = 0.f, p2 = 0.f;
    #pragma unroll
    for (int j = 0; j < 8; ++j) {
        float r = fmaxf(b[ql * 8 + j] + dd * a[j], 0.f);
        const float* wr = Wfc + (size_t)(ql * 8 + j) * 3;
        p0 += r * wr[0]; p1 += r * wr[1]; p2 += r * wr[2];
    }
    #pragma unroll
    for (int off = 8; off > 0; off >>= 1) {
        p0 += __shfl_down(p0, off);
        p1 += __shfl_down(p1, off);
        p2 += __shfl_down(p2, off);
    }
    if (lane == 0) {
        out[(size_t)node * 3 + 0] = tanhf(p0 + bfc[0]);
        out[(size_t)node * 3 + 1] = tanhf(p1 + bfc[1]);
        out[(size_t)node * 3 + 2] = tanhf(p2 + bfc[2]);
    }
}

extern "C" void kernel_launch(void* const* d_in, const int* in_sizes, int n_in,
                              void* d_out, int out_size, void* d_ws, size_t ws_size,
                              hipStream_t stream)
{
    const float* x    = (const float*)d_in[0];
    const int*   edge = (const int*)d_in[1];
    const float* W1   = (const float*)d_in[2];
    const float* b1   = (const float*)d_in[3];
    const float* W2   = (const float*)d_in[4];
    const float* b2   = (const float*)d_in[5];
    const float* Wfc  = (const float*)d_in[6];
    const float* bfc  = (const float*)d_in[7];
    float* out = (float*)d_out;

    const int N = in_sizes[0] / NODE_F;
    const int E = in_sizes[1] / 2;
    const int* src = edge;
    const int* dst = edge + E;

    char* ws = (char*)d_ws;
    size_t off = 0;
    auto alloc = [&](size_t bytes) {
        void* p = ws + off;
        off += (bytes + 511) & ~511ull;
        return p;
    };
    const int nblk = (N + 1023) / 1024;
    float* dinv      = (float*)alloc((size_t)N * 4);
    int*   degE      = (int*)  alloc((size_t)N * 4);
    unsigned short* rank = (unsigned short*)alloc((size_t)E * 2);
    int*   rsA       = (int*)  alloc((size_t)N * 4);
    int*   rsB       = (int*)  alloc((size_t)(N + 1) * 4);
    int*   bsum      = (int*)  alloc((size_t)nblk * 4);
    int*   csr_src   = (int*)  alloc((size_t)E * 4);
    unsigned short* WhiT = (unsigned short*)alloc(2 * 128 * 128 * 2);
    unsigned short* WloT = (unsigned short*)alloc(2 * 128 * 128 * 2);
    __half* H        = (__half*)alloc((size_t)N * NODE_F * 2);
    __half* A1       = (__half*)alloc((size_t)N * NODE_F * 2);
    __half* H2       = (__half*)alloc((size_t)N * NODE_F * 2);
    (void)ws_size; (void)n_in; (void)out_size;

    const int B = 256;
    const int gemm_grid   = (N + 63) / 64;
    const int gather_grid = (N + 3) / 4;
    const int fill_blocks = (E + B - 1) / B;
    const int fin_blocks  = (N + B - 1) / B;

    // 1:4 interleave for gemm1deg
    const int edge_blocks  = (gemm_grid + 3) / 4;
    const int total_blocks = gemm_grid + edge_blocks + 4;

    wconv_kernel<<<2, B, 0, stream>>>(W1, W2, WhiT, WloT);
    hipMemsetAsync(degE, 0, (size_t)N * 4, stream);

    // gemm1 (unscaled H) with deg_rank as interleaved block roles
    gemm1deg_kernel<<<total_blocks, B, 0, stream>>>(
        dst, degE, rank, E, edge_blocks, gemm_grid, x, WhiT, WloT, H, N);

    scan_block_kernel<<<nblk, B, 0, stream>>>(degE, rsA, bsum, N);
    scan_tops_kernel<<<1, 1024, 0, stream>>>(bsum, nblk);

    // [fill csr || finalize row_start + dinv]
    finish_fill_kernel<<<fill_blocks + fin_blocks, B, 0, stream>>>(
        src, dst, rank, rsA, bsum, rsB, dinv, degE, csr_src, E, N, fill_blocks);

    // layer-1 aggregate (per-edge dinv) -> relu -> fp16
    gather1_kernel<<<gather_grid, B, 0, stream>>>(H, csr_src, rsB, dinv, b1, A1, N);

    // layer-2 GEMM (fp16 input, in-register split, scaled epilogue)
    gemm2_kernel<<<gemm_grid, B, 0, stream>>>(A1, WhiT + 128 * 128, WloT + 128 * 128,
                                              dinv, H2, N);

    // layer-2 aggregate + FC head
    gather2fc_kernel<<<gather_grid, B, 0, stream>>>(H2, csr_src, rsB, dinv, b2,
                                                    Wfc, bfc, out, N);
}